// Round 13
// baseline (115.095 us; speedup 1.0000x reference)
//
#include <hip/hip_runtime.h>

// Problem constants
#define BDIM   16
#define PDIM   12
#define TDIM   4096
#define WINW   41
#define PADW   20
#define DDIM   492      // P*WIN
#define KCODES 1024

// fp8 32x32x16 MFMA geometry. Tiles laid out with 32 K-steps (16 KiB) but
// step 31 covers k in [496,512) >= DDIM=492 -> all zeros -> skip it.
#define KS32   32                   // K-steps in the tile LAYOUT
#define KSU    31                   // K-steps actually USED
#define NT32   32                   // code tiles of 32 -> 1024
#define NT32_BYTES (KS32 * 64 * 8)  // 16 KiB per code tile

// R7-R12 lesson: 512-thread blocks get hard-pinned to 128 arch-VGPRs by the
// backend (launch_bounds(512,2), waves_per_eu(2,2), LDS>80KB ALL ignored) and
// our ~135-190-reg live set spilled 9-40 MB of scratch every dispatch.
// 256-thread blocks (R4) are allocated per LDS-limited occupancy: with 68 KiB
// LDS -> 2 blocks/CU -> 8 waves/CU -> 2 waves/SIMD -> 256-VGPR budget.
#define WAVES      4                 // 256-thread blocks
#define ROWS_WAVE  32
#define BMROWS     (WAVES * ROWS_WAVE)   // 128 rows per block
#define MROWS      (BDIM * TDIM)         // 65536
#define NBLK       (MROWS / BMROWS)      // 512 = 2 blocks/CU, all co-resident

#define NBUF   4                    // 64 KiB staging LDS (+4 KiB sb = 68 KiB)
#define DEPTH  2                    // prefetch distance (tiles)

typedef __attribute__((ext_vector_type(16))) float f32x16;

// two f32 pairs -> 4 e4m3 bytes (RNE, saturating) via v_cvt_pk_fp8_f32
__device__ __forceinline__ unsigned int pack4_fp8(float a, float b, float c, float d) {
    int v = 0;
    v = __builtin_amdgcn_cvt_pk_fp8_f32(a, b, v, false);  // bytes 0,1
    v = __builtin_amdgcn_cvt_pk_fp8_f32(c, d, v, true);   // bytes 2,3
    return (unsigned int)v;
}

// Pre-format codebook into fp8 B-fragments for mfma_f32_32x32x16_fp8_fp8.
// frag idx = (nt*KS32 + ks)*64 + lane, 8 bytes each:
//   B[k][n], n = nt*32 + (lane&31), k = ks*16 + (lane>>5)*8 + j  (byte j)
__global__ __launch_bounds__(256) void prep_bfrag_k(const float* __restrict__ cb,
                                                    unsigned long long* __restrict__ bfrag) {
    int idx  = blockIdx.x * 256 + threadIdx.x;   // 0..65535
    int lane = idx & 63;
    int ks   = (idx >> 6) & (KS32 - 1);
    int nt   = idx >> 11;
    int n    = nt * 32 + (lane & 31);
    int hi2  = lane >> 5;
    float v[8];
#pragma unroll
    for (int j = 0; j < 8; ++j) {
        int k = ks * 16 + hi2 * 8 + j;
        v[j] = (k < DDIM) ? cb[n * DDIM + k] : 0.f;
    }
    unsigned int lo = pack4_fp8(v[0], v[1], v[2], v[3]);
    unsigned int hi = pack4_fp8(v[4], v[5], v[6], v[7]);
    bfrag[idx] = ((unsigned long long)hi << 32) | lo;
}

// Exact fp32 code norms.
__global__ __launch_bounds__(64) void prep_cnorm_k(const float* __restrict__ cb,
                                                   float* __restrict__ cnorm) {
    int n = blockIdx.x;
    int lane = threadIdx.x;
    float s = 0.f;
    for (int d = lane; d < DDIM; d += 64) { float c = cb[n * DDIM + d]; s += c * c; }
#pragma unroll
    for (int m = 1; m < 64; m <<= 1) s += __shfl_xor(s, m, 64);
    if (lane == 0) cnorm[n] = s;
}

// Exact sum of ||f||^2 over all rows via window multiplicity:
// mult(tt) = 41 - max(0,20-tt) - max(0,tt-4075).
__global__ __launch_bounds__(256) void xsq_k(const float* __restrict__ x,
                                             float* __restrict__ xsq_part) {
    float s = 0.f;
    for (int i = blockIdx.x * 256 + threadIdx.x; i < BDIM * PDIM * TDIM; i += 256 * 256) {
        int tt = i & (TDIM - 1);
        int mult = WINW - max(0, PADW - tt) - max(0, tt - (TDIM - 1 - PADW));
        float v = x[i];
        s += (float)mult * v * v;
    }
#pragma unroll
    for (int m = 1; m < 64; m <<= 1) s += __shfl_xor(s, m, 64);
    __shared__ float sm[4];
    if ((threadIdx.x & 63) == 0) sm[threadIdx.x >> 6] = s;
    __syncthreads();
    if (threadIdx.x == 0) xsq_part[blockIdx.x] = sm[0] + sm[1] + sm[2] + sm[3];
}

// Stage one 16 KiB code tile into LDS (async, width 16, linear order).
// 4 waves x 4 calls x 64 lanes x 16 B = 16 KiB -> 4 vmcnt slots per stage/wave.
__device__ __forceinline__ void stage_nt(const unsigned char* __restrict__ bfrag,
                                         unsigned char* dst, int nt, int wave, int lane) {
    const unsigned char* g = bfrag + (size_t)nt * NT32_BYTES;
#pragma unroll
    for (int it = 0; it < 4; ++it) {
        int off = it * 4096 + wave * 1024;
        __builtin_amdgcn_global_load_lds(
            (const __attribute__((address_space(1))) unsigned int*)(g + off + lane * 16),
            (__attribute__((address_space(3))) unsigned int*)(dst + off),
            16, 0, 0);
    }
}

// Main sweep: 512 blocks (2/CU, co-resident) x 4 waves x 32 rows.
// fp8 A-slab in registers; codes streamed through four 16 KiB LDS buffers,
// depth-2 prefetch, counted vmcnt (vmcnt(4) steady, vmcnt(0) last tile) +
// raw s_barrier. 2 independent MFMA acc chains; KSU=31 (step 31 all-zero).
// Live regs ~133: afr 62 + acc 32 + bs 16 + bq/ring ~23.
__global__ __launch_bounds__(256)
void vq_main_k(const float* __restrict__ x,
               const unsigned char* __restrict__ bfrag,
               const float* __restrict__ cnorm,
               float* __restrict__ bpart) {
    __shared__ __align__(16) unsigned char smem[NBUF][NT32_BYTES];   // 64 KiB
    __shared__ float sb_lds[KCODES];                                 // 4 KiB
    __shared__ float gsum[2 * WAVES];

    const int lane = threadIdx.x & 63;
    const int wave = threadIdx.x >> 6;
    const int col  = lane & 31;     // B/D column within tile
    const int hi2  = lane >> 5;
    const int rowbase = blockIdx.x * BMROWS + wave * ROWS_WAVE;

    // Depth-2 staging kickoff; latency covered by sb-table + A-build below.
#pragma unroll
    for (int p = 0; p < DEPTH; ++p)
        stage_nt(bfrag, smem[p], p, wave, lane);

    // Bias table: sb_lds[n] = -0.5*||c_n||^2 (4 KiB LDS)
    for (int i = threadIdx.x; i < KCODES; i += 256)
        sb_lds[i] = -0.5f * cnorm[i];

    // ---- Build fp8 A-slab: row = rowbase + col, k = ks*16 + hi2*8 + j ----
    long afr[KSU];
    {
        int row = rowbase + col;
        int b = row >> 12;
        int t = row & (TDIM - 1);
        const float* xb = x + (size_t)b * (PDIM * TDIM);
#pragma unroll
        for (int ks = 0; ks < KSU; ++ks) {
            float v[8];
#pragma unroll
            for (int j = 0; j < 8; ++j) {
                int d = ks * 16 + hi2 * 8 + j;
                float f = 0.f;
                if (d < DDIM) {
                    int p  = d / WINW;
                    int w  = d - p * WINW;
                    int tt = t + w - PADW;
                    if (tt >= 0 && tt < TDIM) f = xb[p * TDIM + tt];
                }
                v[j] = f;
            }
            unsigned int lo = pack4_fp8(v[0], v[1], v[2], v[3]);
            unsigned int hi = pack4_fp8(v[4], v[5], v[6], v[7]);
            afr[ks] = (long)(((unsigned long long)hi << 32) | lo);
        }
    }

    f32x16 bs;
#pragma unroll
    for (int r = 0; r < 16; ++r) bs[r] = -3.0e38f;

    // One full drain at pipeline entry (tiles 0..1 resident; sb_lds visible).
    __syncthreads();

    for (int c = 0; c < NT32; ++c) {
        if (c > 0) {
            // Retire stage(c); stage(c+1) (4 loads) may stay in flight.
            if (c + 1 < NT32) asm volatile("s_waitcnt vmcnt(4)" ::: "memory");
            else              asm volatile("s_waitcnt vmcnt(0)" ::: "memory");
            __builtin_amdgcn_s_barrier();   // tile c complete; old buf free
            __builtin_amdgcn_sched_barrier(0);
        }
        // Prefetch tile c+DEPTH into the buffer freed at tile c-2.
        if (c + DEPTH < NT32) stage_nt(bfrag, smem[(c + DEPTH) % NBUF], c + DEPTH, wave, lane);

        const long* bp = (const long*)(smem[c % NBUF]) + lane;
        f32x16 accA, accB;   // 2 independent chains (32 VGPRs)
#pragma unroll
        for (int r = 0; r < 16; ++r) { accA[r] = 0.f; accB[r] = 0.f; }

        __builtin_amdgcn_s_setprio(1);
#pragma unroll
        for (int ph = 0; ph < 8; ++ph) {
            const int base = ph * 4;
            const int nk = (base + 4 <= KSU) ? 4 : (KSU - base);   // 4,..,4,3
            long bq[4];
#pragma unroll
            for (int i = 0; i < 4; ++i) if (i < nk) bq[i] = bp[(base + i) * 64];
#pragma unroll
            for (int i = 0; i < 4; ++i) {
                if (i < nk) {
                    if ((i & 1) == 0)
                        accA = __builtin_amdgcn_mfma_f32_32x32x16_fp8_fp8(afr[base + i], bq[i], accA, 0, 0, 0);
                    else
                        accB = __builtin_amdgcn_mfma_f32_32x32x16_fp8_fp8(afr[base + i], bq[i], accB, 0, 0, 0);
                }
            }
        }
        __builtin_amdgcn_s_setprio(0);

        const float sb = sb_lds[c * 32 + col];   // ds_read (lgkmcnt, not vmcnt)
#pragma unroll
        for (int r = 0; r < 16; ++r)
            bs[r] = fmaxf(bs[r], accA[r] + accB[r] + sb);
    }

    // ---- Per-row max across the 32 col-lanes (masks<32 preserve hi2) ----
#pragma unroll
    for (int m = 1; m < 32; m <<= 1)
#pragma unroll
        for (int r = 0; r < 16; ++r)
            bs[r] = fmaxf(bs[r], __shfl_xor(bs[r], m, 64));

    // D rows: row = (r&3) + 8*(r>>2) + 4*hi2 — bijective over 32 rows per
    // (hi2, r); sum over all rows is mapping-invariant.
    if (col == 0) {
        float s = 0.f;
#pragma unroll
        for (int r = 0; r < 16; ++r) s += bs[r];
        gsum[wave * 2 + hi2] = s;
    }
    __syncthreads();
    if (threadIdx.x == 0) {
        float tot = 0.f;
#pragma unroll
        for (int i = 0; i < 2 * WAVES; ++i) tot += gsum[i];
        bpart[blockIdx.x] = tot;
    }
}

// loss = 0.25 * (Sxx - 2*sum_blocks bpart) / (65536*492)
__global__ __launch_bounds__(256) void finalize_k(const float* __restrict__ bpart,
                                                  const float* __restrict__ xsq_part,
                                                  float* __restrict__ out) {
    __shared__ double sm[256];
    int tid = threadIdx.x;
    sm[tid] = (double)bpart[tid] + (double)bpart[tid + 256];
    __syncthreads();
    for (int st = 128; st > 0; st >>= 1) {
        if (tid < st) sm[tid] += sm[tid + st];
        __syncthreads();
    }
    double S1 = sm[0];
    __syncthreads();
    sm[tid] = (double)xsq_part[tid];
    __syncthreads();
    for (int st = 128; st > 0; st >>= 1) {
        if (tid < st) sm[tid] += sm[tid + st];
        __syncthreads();
    }
    if (tid == 0)
        out[0] = (float)(0.25 * (sm[0] - 2.0 * S1) / ((double)MROWS * (double)DDIM));
}

extern "C" void kernel_launch(void* const* d_in, const int* in_sizes, int n_in,
                              void* d_out, int out_size, void* d_ws, size_t ws_size,
                              hipStream_t stream) {
    const float* x  = (const float*)d_in[0];   // (16,12,4096) f32
    const float* cb = (const float*)d_in[1];   // (1024,492) f32
    float* out = (float*)d_out;

    // workspace layout (~524 KiB)
    char* ws = (char*)d_ws;
    unsigned long long* bfrag = (unsigned long long*)ws;            // 512 KiB
    float* cnorm    = (float*)(ws + (512u << 10));                  // 4 KiB
    float* xsq_part = (float*)(ws + (512u << 10) + 4096);           // 1 KiB
    float* bpart    = (float*)(ws + (512u << 10) + 8192);           // 2 KiB

    prep_bfrag_k<<<256, 256, 0, stream>>>(cb, bfrag);
    prep_cnorm_k<<<KCODES, 64, 0, stream>>>(cb, cnorm);
    xsq_k<<<256, 256, 0, stream>>>(x, xsq_part);
    vq_main_k<<<NBLK, 256, 0, stream>>>(x, (const unsigned char*)bfrag, cnorm, bpart);
    finalize_k<<<1, 256, 0, stream>>>(bpart, xsq_part, out);
}

// Round 14
// 80.603 us; speedup vs baseline: 1.4279x; 1.4279x over previous
//
#include <hip/hip_runtime.h>

// Problem constants
#define BDIM   16
#define PDIM   12
#define TDIM   4096
#define WINW   41
#define PADW   20
#define DDIM   492      // P*WIN
#define KCODES 1024

// fp8 32x32x16 MFMA geometry. Tiles laid out with 32 K-steps (16 KiB) but
// step 31 covers k in [496,512) >= DDIM=492 -> all zeros -> skip it.
#define KS32   32                   // K-steps in the tile LAYOUT
#define KSU    31                   // K-steps actually USED
#define NT32   32                   // code tiles of 32 -> 1024
#define NT32_BYTES (KS32 * 64 * 8)  // 16 KiB per code tile

// R13 lesson: resident waves/CU == ONE BLOCK's waves (2-blocks/CU never
// co-resides: 256-thr blocks -> occ 11%, 130us). So keep 512-thr/8-wave
// blocks (occ 21%, 95us best) and instead fit the live set under the
// 128-VGPR cap the backend pins for 512-thr blocks (R7-R12: launch_bounds /
// waves_per_eu / LDS-size all failed to move it).
#define WAVES      8                 // 512-thread blocks
#define ROWS_WAVE  32
#define BMROWS     (WAVES * ROWS_WAVE)   // 256 rows per block
#define MROWS      (BDIM * TDIM)         // 65536
#define NBLK       (MROWS / BMROWS)      // 256 = exactly 1 block/CU

#define NBUF   6                    // 96 KiB staging LDS
#define DEPTH  4                    // prefetch distance

typedef __attribute__((ext_vector_type(16))) float f32x16;

// two f32 pairs -> 4 e4m3 bytes (RNE, saturating) via v_cvt_pk_fp8_f32
__device__ __forceinline__ unsigned int pack4_fp8(float a, float b, float c, float d) {
    int v = 0;
    v = __builtin_amdgcn_cvt_pk_fp8_f32(a, b, v, false);  // bytes 0,1
    v = __builtin_amdgcn_cvt_pk_fp8_f32(c, d, v, true);   // bytes 2,3
    return (unsigned int)v;
}

// Pre-format codebook into fp8 B-fragments for mfma_f32_32x32x16_fp8_fp8.
// frag idx = (nt*KS32 + ks)*64 + lane, 8 bytes each:
//   B[k][n], n = nt*32 + (lane&31), k = ks*16 + (lane>>5)*8 + j  (byte j)
__global__ __launch_bounds__(256) void prep_bfrag_k(const float* __restrict__ cb,
                                                    unsigned long long* __restrict__ bfrag) {
    int idx  = blockIdx.x * 256 + threadIdx.x;   // 0..65535
    int lane = idx & 63;
    int ks   = (idx >> 6) & (KS32 - 1);
    int nt   = idx >> 11;
    int n    = nt * 32 + (lane & 31);
    int hi2  = lane >> 5;
    float v[8];
#pragma unroll
    for (int j = 0; j < 8; ++j) {
        int k = ks * 16 + hi2 * 8 + j;
        v[j] = (k < DDIM) ? cb[n * DDIM + k] : 0.f;
    }
    unsigned int lo = pack4_fp8(v[0], v[1], v[2], v[3]);
    unsigned int hi = pack4_fp8(v[4], v[5], v[6], v[7]);
    bfrag[idx] = ((unsigned long long)hi << 32) | lo;
}

// Exact fp32 code norms.
__global__ __launch_bounds__(64) void prep_cnorm_k(const float* __restrict__ cb,
                                                   float* __restrict__ cnorm) {
    int n = blockIdx.x;
    int lane = threadIdx.x;
    float s = 0.f;
    for (int d = lane; d < DDIM; d += 64) { float c = cb[n * DDIM + d]; s += c * c; }
#pragma unroll
    for (int m = 1; m < 64; m <<= 1) s += __shfl_xor(s, m, 64);
    if (lane == 0) cnorm[n] = s;
}

// Exact sum of ||f||^2 over all rows via window multiplicity:
// mult(tt) = 41 - max(0,20-tt) - max(0,tt-4075).
__global__ __launch_bounds__(256) void xsq_k(const float* __restrict__ x,
                                             float* __restrict__ xsq_part) {
    float s = 0.f;
    for (int i = blockIdx.x * 256 + threadIdx.x; i < BDIM * PDIM * TDIM; i += 256 * 256) {
        int tt = i & (TDIM - 1);
        int mult = WINW - max(0, PADW - tt) - max(0, tt - (TDIM - 1 - PADW));
        float v = x[i];
        s += (float)mult * v * v;
    }
#pragma unroll
    for (int m = 1; m < 64; m <<= 1) s += __shfl_xor(s, m, 64);
    __shared__ float sm[4];
    if ((threadIdx.x & 63) == 0) sm[threadIdx.x >> 6] = s;
    __syncthreads();
    if (threadIdx.x == 0) xsq_part[blockIdx.x] = sm[0] + sm[1] + sm[2] + sm[3];
}

// Stage one 16 KiB code tile into LDS (async, width 16, linear order).
// 8 waves x 2 calls x 64 lanes x 16 B = 16 KiB -> 2 vmcnt slots per stage/wave.
__device__ __forceinline__ void stage_nt(const unsigned char* __restrict__ bfrag,
                                         unsigned char* dst, int nt, int wave, int lane) {
    const unsigned char* g = bfrag + (size_t)nt * NT32_BYTES;
#pragma unroll
    for (int it = 0; it < 2; ++it) {
        int off = wave * 2048 + it * 1024;
        __builtin_amdgcn_global_load_lds(
            (const __attribute__((address_space(1))) unsigned int*)(g + off + lane * 16),
            (__attribute__((address_space(3))) unsigned int*)(dst + off),
            16, 0, 0);
    }
}

// Main sweep: 256 blocks (1/CU) x 8 waves x 32 rows. fp8 A-slab in registers;
// codes streamed through six 16 KiB LDS buffers, depth-4 prefetch, counted
// vmcnt + raw s_barrier (R11 schedule, unchanged).
//
// SINGLE acc chain (R14): live regs ~115 = afr 62 + acc 16 + bs 16 + bq 4 +
// addr ~15 -> fits the pinned 128 cap, NO spill (R11 spilled ~18 regs ->
// 9.2 MB scratch). Dep-chain safety: one 32x32 MFMA occupies the SIMD ~37cyc;
// 2 waves/SIMD round-robin -> >=74cyc between dependent issues.
__global__ __launch_bounds__(512)
void vq_main_k(const float* __restrict__ x,
               const unsigned char* __restrict__ bfrag,
               const float* __restrict__ cnorm,
               float* __restrict__ bpart) {
    __shared__ __align__(16) unsigned char smem[NBUF][NT32_BYTES];   // 96 KiB
    __shared__ float sb_lds[KCODES];                                 // 4 KiB
    __shared__ float gsum[2 * WAVES];

    const int lane = threadIdx.x & 63;
    const int wave = threadIdx.x >> 6;
    const int col  = lane & 31;     // B/D column within tile
    const int hi2  = lane >> 5;
    const int rowbase = blockIdx.x * BMROWS + wave * ROWS_WAVE;

    // Depth-4 staging kickoff; latency covered by sb-table + A-build below.
#pragma unroll
    for (int p = 0; p < DEPTH; ++p)
        stage_nt(bfrag, smem[p], p, wave, lane);

    // Bias table: sb_lds[n] = -0.5*||c_n||^2 (4 KiB LDS)
    for (int i = threadIdx.x; i < KCODES; i += 512)
        sb_lds[i] = -0.5f * cnorm[i];

    // ---- Build fp8 A-slab: row = rowbase + col, k = ks*16 + hi2*8 + j ----
    long afr[KSU];
    {
        int row = rowbase + col;
        int b = row >> 12;
        int t = row & (TDIM - 1);
        const float* xb = x + (size_t)b * (PDIM * TDIM);
#pragma unroll
        for (int ks = 0; ks < KSU; ++ks) {
            float v[8];
#pragma unroll
            for (int j = 0; j < 8; ++j) {
                int d = ks * 16 + hi2 * 8 + j;
                float f = 0.f;
                if (d < DDIM) {
                    int p  = d / WINW;
                    int w  = d - p * WINW;
                    int tt = t + w - PADW;
                    if (tt >= 0 && tt < TDIM) f = xb[p * TDIM + tt];
                }
                v[j] = f;
            }
            unsigned int lo = pack4_fp8(v[0], v[1], v[2], v[3]);
            unsigned int hi = pack4_fp8(v[4], v[5], v[6], v[7]);
            afr[ks] = (long)(((unsigned long long)hi << 32) | lo);
        }
    }

    f32x16 bs;
#pragma unroll
    for (int r = 0; r < 16; ++r) bs[r] = -3.0e38f;

    // One full drain at pipeline entry (tiles 0..3 resident; sb_lds visible).
    __syncthreads();

    for (int c = 0; c < NT32; ++c) {
        if (c > 0) {
            // Ensure stage(c) retired; later stages (2 loads each) may remain
            // in flight across the barrier (T4 counted-vmcnt).
            int rem = NT32 - 1 - c;   // stages issued beyond c
            if (rem >= 3)      asm volatile("s_waitcnt vmcnt(6)" ::: "memory");
            else if (rem == 2) asm volatile("s_waitcnt vmcnt(4)" ::: "memory");
            else if (rem == 1) asm volatile("s_waitcnt vmcnt(2)" ::: "memory");
            else               asm volatile("s_waitcnt vmcnt(0)" ::: "memory");
            __builtin_amdgcn_s_barrier();   // tile c complete; buf[(c-2)%NBUF] free
            __builtin_amdgcn_sched_barrier(0);
        }
        // Prefetch tile c+DEPTH into buf freed at tile c-2 (barrier-protected).
        if (c + DEPTH < NT32) stage_nt(bfrag, smem[(c + DEPTH) % NBUF], c + DEPTH, wave, lane);

        const long* bp = (const long*)(smem[c % NBUF]) + lane;
        f32x16 acc;   // single chain (16 VGPRs)
#pragma unroll
        for (int r = 0; r < 16; ++r) acc[r] = 0.f;

        __builtin_amdgcn_s_setprio(1);
#pragma unroll
        for (int ks = 0; ks < KSU; ++ks) {
            long bq = bp[ks * 64];
            acc = __builtin_amdgcn_mfma_f32_32x32x16_fp8_fp8(afr[ks], bq, acc, 0, 0, 0);
        }
        __builtin_amdgcn_s_setprio(0);

        const float sb = sb_lds[c * 32 + col];   // ds_read (lgkmcnt, not vmcnt)
#pragma unroll
        for (int r = 0; r < 16; ++r)
            bs[r] = fmaxf(bs[r], acc[r] + sb);
    }

    // ---- Per-row max across the 32 col-lanes (masks<32 preserve hi2) ----
#pragma unroll
    for (int m = 1; m < 32; m <<= 1)
#pragma unroll
        for (int r = 0; r < 16; ++r)
            bs[r] = fmaxf(bs[r], __shfl_xor(bs[r], m, 64));

    // D rows: row = (r&3) + 8*(r>>2) + 4*hi2 — bijective over 32 rows per
    // (hi2, r); sum over all rows is mapping-invariant.
    if (col == 0) {
        float s = 0.f;
#pragma unroll
        for (int r = 0; r < 16; ++r) s += bs[r];
        gsum[wave * 2 + hi2] = s;
    }
    __syncthreads();
    if (threadIdx.x == 0) {
        float tot = 0.f;
#pragma unroll
        for (int i = 0; i < 2 * WAVES; ++i) tot += gsum[i];
        bpart[blockIdx.x] = tot;
    }
}

// loss = 0.25 * (Sxx - 2*sum_blocks bpart) / (65536*492)
__global__ __launch_bounds__(256) void finalize_k(const float* __restrict__ bpart,
                                                  const float* __restrict__ xsq_part,
                                                  float* __restrict__ out) {
    __shared__ double sm[256];
    int tid = threadIdx.x;
    sm[tid] = (double)bpart[tid];
    __syncthreads();
    for (int st = 128; st > 0; st >>= 1) {
        if (tid < st) sm[tid] += sm[tid + st];
        __syncthreads();
    }
    double S1 = sm[0];
    __syncthreads();
    sm[tid] = (double)xsq_part[tid];
    __syncthreads();
    for (int st = 128; st > 0; st >>= 1) {
        if (tid < st) sm[tid] += sm[tid + st];
        __syncthreads();
    }
    if (tid == 0)
        out[0] = (float)(0.25 * (sm[0] - 2.0 * S1) / ((double)MROWS * (double)DDIM));
}

extern "C" void kernel_launch(void* const* d_in, const int* in_sizes, int n_in,
                              void* d_out, int out_size, void* d_ws, size_t ws_size,
                              hipStream_t stream) {
    const float* x  = (const float*)d_in[0];   // (16,12,4096) f32
    const float* cb = (const float*)d_in[1];   // (1024,492) f32
    float* out = (float*)d_out;

    // workspace layout (~524 KiB)
    char* ws = (char*)d_ws;
    unsigned long long* bfrag = (unsigned long long*)ws;            // 512 KiB
    float* cnorm    = (float*)(ws + (512u << 10));                  // 4 KiB
    float* xsq_part = (float*)(ws + (512u << 10) + 4096);           // 1 KiB
    float* bpart    = (float*)(ws + (512u << 10) + 8192);           // 1 KiB

    prep_bfrag_k<<<256, 256, 0, stream>>>(cb, bfrag);
    prep_cnorm_k<<<KCODES, 64, 0, stream>>>(cb, cnorm);
    xsq_k<<<256, 256, 0, stream>>>(x, xsq_part);
    vq_main_k<<<NBLK, 512, 0, stream>>>(x, (const unsigned char*)bfrag, cnorm, bpart);
    finalize_k<<<1, 256, 0, stream>>>(bpart, xsq_part, out);
}